// Round 5
// baseline (467.862 us; speedup 1.0000x reference)
//
#include <hip/hip_runtime.h>
#include <hip/hip_bf16.h>
#include <stdint.h>

// QuantizedCpuLinear: y = scale * (x @ wq^T)
// x: f32 [8192,4096]; wq int8-valued delivered as int32 [4096,4096] (K contig);
// out f32 [8192,4096]. bf16 MFMA GEMM, 256x256 tile, BK=64, 8 waves.
// R5 = R2 skeleton, but B operand bypasses LDS: per-wave B fragments load
// global->register (double-buffered bP/bQ, 1 tile ahead). LDS holds A only
// (64 KiB): LDS service drops below the MFMA-pipe floor. A staged via
// global_load_lds with inverse-swizzled source (rule 21), swizzled reads (T2),
// counted vmcnt (T4), setprio (T5), XCD swz (T1). MFMA ks-outermost for
// independence (bit-identical accumulation order).

#define M_DIM 8192
#define N_DIM 4096
#define K_DIM 4096
#define BM 256
#define BN 256
#define BK 64
#define NT (K_DIM / BK)          // 64

typedef __attribute__((ext_vector_type(4))) float    f32x4;
typedef __attribute__((ext_vector_type(4))) int      i32x4;
typedef __attribute__((ext_vector_type(2))) uint32_t u32x2;
typedef __attribute__((ext_vector_type(4))) uint32_t u32x4;
typedef __attribute__((ext_vector_type(8))) short    bf16x8;
typedef uint32_t u32;

__device__ __forceinline__ u32 fbits(float f) { return __builtin_bit_cast(u32, f); }
// two f32 -> two bf16 by truncation (1 v_perm_b32); exact for int8-valued floats.
__device__ __forceinline__ u32 pack_bf16_trunc(float lo, float hi) {
    return __builtin_amdgcn_perm(fbits(hi), fbits(lo), 0x07060302u);
}
// LDS byte address for logical (row, byte-col) in a [256][128B] tile (fallback).
__device__ __forceinline__ int swzb(int row, int bytecol) {
    return row * 128 + (bytecol ^ ((row & 7) << 4));
}

// global_load_lds, 16B per lane. LDS dst is wave-uniform; HW writes dst+lane*16.
__device__ __forceinline__ void gload_lds16(const void* g, void* s) {
    __builtin_amdgcn_global_load_lds(
        (const __attribute__((address_space(1))) void*)(uintptr_t)g,
        (__attribute__((address_space(3))) void*)(u32)(uintptr_t)s, 16, 0, 0);
}

#define WAIT_VM8()   do { asm volatile("s_waitcnt vmcnt(8)" ::: "memory");   \
                          __builtin_amdgcn_sched_barrier(0); } while (0)
#define WAIT_VM0()   do { asm volatile("s_waitcnt vmcnt(0)" ::: "memory");   \
                          __builtin_amdgcn_sched_barrier(0); } while (0)
#define BARRIER()    do { __builtin_amdgcn_s_barrier();                      \
                          __builtin_amdgcn_sched_barrier(0); } while (0)

// ---- pre-convert: W int32 -> bf16 (same layout) ----
__global__ __launch_bounds__(256)
void qlin_convert_w(const int* __restrict__ Wq, short* __restrict__ Wb)
{
    const size_t i = (size_t)blockIdx.x * 256 + threadIdx.x;   // 8 elts/thread
    i32x4 w0 = ((const i32x4*)Wq)[2 * i];
    i32x4 w1 = ((const i32x4*)Wq)[2 * i + 1];
    u32x4 q;
    q[0] = pack_bf16_trunc((float)w0[0], (float)w0[1]);
    q[1] = pack_bf16_trunc((float)w0[2], (float)w0[3]);
    q[2] = pack_bf16_trunc((float)w1[0], (float)w1[1]);
    q[3] = pack_bf16_trunc((float)w1[2], (float)w1[3]);
    ((u32x4*)Wb)[i] = q;
}

// ---- pre-convert: X f32 -> bf16 ----
__global__ __launch_bounds__(256)
void qlin_convert_x(const float* __restrict__ X, short* __restrict__ Xb)
{
    const size_t i = (size_t)blockIdx.x * 256 + threadIdx.x;   // 8 elts/thread
    f32x4 a = ((const f32x4*)X)[2 * i];
    f32x4 b = ((const f32x4*)X)[2 * i + 1];
    u32x4 q;
    q[0] = pack_bf16_trunc(a[0], a[1]);
    q[1] = pack_bf16_trunc(a[2], a[3]);
    q[2] = pack_bf16_trunc(b[0], b[1]);
    q[3] = pack_bf16_trunc(b[2], b[3]);
    ((u32x4*)Xb)[i] = q;
}

// ===================== main pipelined GEMM (bf16 inputs) =====================
// LDS: A only, [2 dbuf][2 half][128 rows][128 B] = 64 KiB. Logical (row,bytecol)
// at physical row*128 + (bytecol ^ ((row&7)<<4)); global source pre-swizzled
// with the same XOR so the linear DMA write lands swizzled (rule 21).
// B: per-wave fragments straight from global (L2) into registers, double-
// buffered across tiles. Each fragment load: 16 rows x 64 contiguous bytes.
__global__ __launch_bounds__(512, 2)
void qlin_gemm_p(const short* __restrict__ A, const short* __restrict__ B,
                 const float* __restrict__ scale_p, float* __restrict__ C)
{
    __shared__ __align__(16) char As[2][2][128 * 128];   // 64 KiB (A only)

    const int tid = threadIdx.x;
    // XCD swizzle: nwg = 512, divisible by 8 -> bijective
    const int nwg = (M_DIM / BM) * (N_DIM / BN);   // 512
    const int cpx = nwg / 8;
    const int bid = ((int)blockIdx.x % 8) * cpx + (int)blockIdx.x / 8;
    const int tileM = (bid / (N_DIM / BN)) * BM;
    const int tileN = (bid % (N_DIM / BN)) * BN;

    const int lane = tid & 63;
    const int wid  = tid >> 6;       // 0..7
    const int wr   = wid >> 2;       // 0..1  (wave covers 128 M-rows = A half wr)
    const int wc   = wid & 3;        // 0..3  (wave covers 64 N-cols)
    const int lr   = lane & 15;
    const int lq   = lane >> 4;

    // A staging source addressing (per lane): 8 rows x 128B per wave-issue
    const int srow = lane >> 3;                    // 0..7
    const int scol = ((lane & 7) ^ srow) << 4;     // inverse-swizzled byte col
    const char* Ag = (const char*)A;
    const char* Bg = (const char*)B;

    // stage one A half-tile (2 x global_load_lds per thread); 4 DMA per tile
    auto stageA = [&](int buf, int h, int kt) {
#pragma unroll
        for (int j = 0; j < 2; ++j) {
            const int seg = wid * 2 + j;           // 0..15
            const char* src = Ag + (size_t)(tileM + h * 128 + seg * 8 + srow) * (K_DIM * 2)
                                 + kt * (BK * 2) + scol;
            gload_lds16(src, &As[buf][h][seg * 1024]);
        }
    };

    // B fragment base: row = tileN + wc*64 + nb*16 + lr, bytes kt*128 + ks*64 + lq*16
    const char* bbase = Bg + (size_t)(tileN + wc * 64 + lr) * (K_DIM * 2) + lq * 16;
    auto ldBg = [&](bf16x8 (&bf)[4][2], int kt) {
#pragma unroll
        for (int nb = 0; nb < 4; ++nb)
#pragma unroll
            for (int ks = 0; ks < 2; ++ks)
                bf[nb][ks] = *(const bf16x8*)(bbase + (size_t)(nb * 16) * (K_DIM * 2)
                                              + kt * (BK * 2) + ks * 64);
    };

    // ---- fragments ----
    f32x4  acc[8][4] = {};
    bf16x8 afr[4][2];                // reused mb0-3 then mb4-7
    bf16x8 bP[4][2], bQ[4][2];       // B double-buffer (static indexing)

    auto swzh = [](int row, int bc) { return row * 128 + (bc ^ ((row & 7) << 4)); };
    auto ldA = [&](int buf, int mb) {
#pragma unroll
        for (int m = 0; m < 4; ++m) {
            const int row = (mb + m) * 16 + lr;                 // 0..127 in half wr
#pragma unroll
            for (int ks = 0; ks < 2; ++ks)
                afr[m][ks] = *(const bf16x8*)&As[buf][wr][swzh(row, ks * 64 + lq * 16)];
        }
    };
    // 32 MFMA covering (mb..mb+3) x all 4 nb. ks OUTER: 16 independent MFMAs
    // per ks-slice (acc order per element still ks0 then ks1 -> bit-identical).
    auto quadrow = [&](int mb, bf16x8 (&bf)[4][2]) {
        __builtin_amdgcn_s_setprio(1);
#pragma unroll
        for (int ks = 0; ks < 2; ++ks)
#pragma unroll
            for (int m = 0; m < 4; ++m)
#pragma unroll
                for (int nb = 0; nb < 4; ++nb)
                    acc[mb + m][nb] = __builtin_amdgcn_mfma_f32_16x16x32_bf16(
                        afr[m][ks], bf[nb][ks], acc[mb + m][nb], 0, 0, 0);
        __builtin_amdgcn_s_setprio(0);
    };

    // ---- prologue ----
    stageA(0, 0, 0); stageA(0, 1, 0);   // A(0): 4 DMA
    ldBg(bP, 0);                        // B(0): 8 loads
    ldBg(bQ, 1);                        // B(1): 8 loads
    WAIT_VM8();        // FIFO [A0:4, B0:8, B1:8]=20 -> leaves B1; A0,B0 landed
    BARRIER();

    // ---- main loop, 1 barrier + 1 counted vmcnt per K-tile, x2 unrolled ----
    // Entry invariant tile t (buf c=t&1): A(t) in LDS buf c; B(t) in bCur regs;
    // B(t+1) [8] in flight toward bNxt. Body: issue A(t+1) DMA (buf c^1 free
    // since end of t-1) -> ldA/quad x2 -> issue B(t+2) into bCur (regs consumed)
    // -> vmcnt(8): FIFO [B(t+1):8, A(t+1):4, B(t+2):8]=20, leaves B(t+2);
    // A(t+1)+B(t+1) landed -> barrier.
    auto body = [&](int kt, int cur, bf16x8 (&bCur)[4][2]) {
        const int nxt = cur ^ 1;
        if (kt + 1 < NT) { stageA(nxt, 0, kt + 1); stageA(nxt, 1, kt + 1); }

        ldA(cur, 0);                 // 8 ds_reads
        quadrow(0, bCur);            // 32 MFMA (B from regs: no lgkm wait)
        ldA(cur, 4);                 // 8 ds_reads (afr reuse)
        quadrow(4, bCur);            // 32 MFMA

        if (kt + 2 < NT) { ldBg(bCur, kt + 2); WAIT_VM8(); }
        else if (kt + 1 < NT) { WAIT_VM0(); }   // tail tiles: cheap drain
        BARRIER();
    };

#pragma unroll 1
    for (int kt = 0; kt < NT; kt += 2) {
        body(kt,     0, bP);
        body(kt + 1, 1, bQ);
    }

    // ---- epilogue: C/D layout col=lane&15, row=(lane>>4)*4+reg ----
    const float scl = scale_p[0];
#pragma unroll
    for (int m = 0; m < 8; ++m) {
        const int gm0 = tileM + wr * 128 + m * 16 + lq * 4;
#pragma unroll
        for (int n = 0; n < 4; ++n) {
            const int gn = tileN + wc * 64 + n * 16 + lr;
            float* cp = C + (size_t)gm0 * N_DIM + gn;
#pragma unroll
            for (int r = 0; r < 4; ++r)
                cp[(size_t)r * N_DIM] = acc[m][n][r] * scl;
        }
    }
}

// ===================== fallback (no workspace): reg-staged kernel ============
#define TILE_BYTES (BM * BK * 2)
__global__ __launch_bounds__(512, 2)
void qlin_gemm8(const void* __restrict__ Asrc, const void* __restrict__ Bsrc,
                const float* __restrict__ scale_p, float* __restrict__ C)
{
    __shared__ char As[2 * TILE_BYTES];
    __shared__ char Bs[2 * TILE_BYTES];

    const int tid = threadIdx.x;
    const int nwg = (M_DIM / BM) * (N_DIM / BN);
    const int cpx = nwg / 8;
    const int bid = ((int)blockIdx.x % 8) * cpx + (int)blockIdx.x / 8;
    const int tileM = (bid / (N_DIM / BN)) * BM;
    const int tileN = (bid % (N_DIM / BN)) * BN;

    const int lane = tid & 63;
    const int wid  = tid >> 6;
    const int wr   = wid >> 2;
    const int wc   = wid & 3;
    const int lr   = lane & 15;
    const int lq   = lane >> 4;

    f32x4  aF[8]; i32x4 wF[8];

    const float* ag0 = (const float*)Asrc + (size_t)(tileM + (tid >> 4)) * K_DIM + (tid & 15) * 4;
    const int*   bg0 = (const int*)Bsrc  + (size_t)(tileN + (tid >> 4)) * K_DIM + (tid & 15) * 4;

    auto stage_load = [&](int kt) {
#pragma unroll
        for (int i = 0; i < 8; ++i)
            aF[i] = *(const f32x4*)(ag0 + (size_t)(32 * i) * K_DIM + kt * BK);
#pragma unroll
        for (int i = 0; i < 8; ++i)
            wF[i] = *(const i32x4*)(bg0 + (size_t)(32 * i) * K_DIM + kt * BK);
    };
    auto stage_writeA = [&](int nxt) {
        char* dst = As + nxt * TILE_BYTES;
#pragma unroll
        for (int i = 0; i < 8; ++i) {
            u32x2 p;
            p[0] = pack_bf16_trunc(aF[i][0], aF[i][1]);
            p[1] = pack_bf16_trunc(aF[i][2], aF[i][3]);
            *(u32x2*)(dst + swzb((tid >> 4) + 32 * i, (tid & 15) * 8)) = p;
        }
    };
    auto stage_writeB = [&](int nxt) {
        char* dst = Bs + nxt * TILE_BYTES;
#pragma unroll
        for (int i = 0; i < 8; ++i) {
            u32x2 p;
            p[0] = pack_bf16_trunc((float)wF[i][0], (float)wF[i][1]);
            p[1] = pack_bf16_trunc((float)wF[i][2], (float)wF[i][3]);
            *(u32x2*)(dst + swzb((tid >> 4) + 32 * i, (tid & 15) * 8)) = p;
        }
    };

    f32x4  acc[8][4] = {};
    bf16x8 afr[4][2], bfr[2][2];

    auto ldA = [&](const char* buf, int mb) {
#pragma unroll
        for (int m = 0; m < 4; ++m) {
            const int row = wr * 128 + (mb + m) * 16 + lr;
#pragma unroll
            for (int ks = 0; ks < 2; ++ks)
                afr[m][ks] = *(const bf16x8*)(buf + swzb(row, ks * 64 + lq * 16));
        }
    };
    auto ldB = [&](const char* buf, int nb) {
#pragma unroll
        for (int n = 0; n < 2; ++n) {
            const int row = wc * 64 + (nb + n) * 16 + lr;
#pragma unroll
            for (int ks = 0; ks < 2; ++ks)
                bfr[n][ks] = *(const bf16x8*)(buf + swzb(row, ks * 64 + lq * 16));
        }
    };
    auto quad = [&](int mb, int nb) {
        __builtin_amdgcn_s_setprio(1);
#pragma unroll
        for (int m = 0; m < 4; ++m)
#pragma unroll
            for (int n = 0; n < 2; ++n)
#pragma unroll
                for (int ks = 0; ks < 2; ++ks)
                    acc[mb + m][nb + n] = __builtin_amdgcn_mfma_f32_16x16x32_bf16(
                        afr[m][ks], bfr[n][ks], acc[mb + m][nb + n], 0, 0, 0);
        __builtin_amdgcn_s_setprio(0);
    };

    stage_load(0);
    stage_writeA(0);
    stage_writeB(0);
    __syncthreads();

#pragma unroll 1
    for (int kt = 0; kt < NT; ++kt) {
        const int cur = kt & 1, nxt = cur ^ 1;
        const bool more = (kt + 1) < NT;
        const char* Ab = As + cur * TILE_BYTES;
        const char* Bb = Bs + cur * TILE_BYTES;

        if (more) stage_load(kt + 1);

        ldA(Ab, 0); ldB(Bb, 0); quad(0, 0);
        ldB(Bb, 2);             quad(0, 2);
        ldA(Ab, 4);
        if (more) stage_writeA(nxt);
        quad(4, 2);
        ldB(Bb, 0);
        if (more) stage_writeB(nxt);
        quad(4, 0);

        __syncthreads();
    }

    const float scl = scale_p[0];
#pragma unroll
    for (int m = 0; m < 8; ++m) {
        const int gm0 = tileM + wr * 128 + m * 16 + lq * 4;
#pragma unroll
        for (int n = 0; n < 4; ++n) {
            const int gn = tileN + wc * 64 + n * 16 + lr;
            float* cp = C + (size_t)gm0 * N_DIM + gn;
#pragma unroll
            for (int r = 0; r < 4; ++r)
                cp[(size_t)r * N_DIM] = acc[m][n][r] * scl;
        }
    }
}

extern "C" void kernel_launch(void* const* d_in, const int* in_sizes, int n_in,
                              void* d_out, int out_size, void* d_ws, size_t ws_size,
                              hipStream_t stream)
{
    (void)in_sizes; (void)n_in; (void)out_size;
    const float* X     = (const float*)d_in[0];
    const int*   Wq    = (const int*)d_in[1];      // int8-valued, delivered as int32
    const float* scale = (const float*)d_in[2];
    float* C = (float*)d_out;

    const dim3 gblock(256);
    const dim3 ggrid((M_DIM / BM) * (N_DIM / BN));  // 512
    const size_t xbytes = (size_t)M_DIM * K_DIM * sizeof(short);   // 64 MiB
    const size_t wbytes = (size_t)N_DIM * K_DIM * sizeof(short);   // 32 MiB

    if (ws_size >= xbytes + wbytes) {
        short* Xb = (short*)d_ws;
        short* Wb = (short*)((char*)d_ws + xbytes);
        qlin_convert_x<<<dim3((size_t)M_DIM * K_DIM / (8 * 256)), gblock, 0, stream>>>(X, Xb);
        qlin_convert_w<<<dim3((size_t)N_DIM * K_DIM / (8 * 256)), gblock, 0, stream>>>(Wq, Wb);
        qlin_gemm_p<<<ggrid, dim3(512), 0, stream>>>(Xb, Wb, scale, C);
    } else {
        qlin_gemm8<<<ggrid, dim3(512), 0, stream>>>(X, Wq, scale, C);
    }
}

// Round 6
// 302.957 us; speedup vs baseline: 1.5443x; 1.5443x over previous
//
#include <hip/hip_runtime.h>
#include <hip/hip_bf16.h>
#include <stdint.h>

// QuantizedCpuLinear: y = scale * (x @ wq^T)
// x: f32 [8192,4096]; wq int8-valued delivered as int32 [4096,4096] (K contig);
// out f32 [8192,4096]. bf16 MFMA GEMM, 256x256 tile, BK=64, 8 waves.
// R6 = R2 skeleton (2 barriers + counted vmcnt(4) per K-tile, dbuf swizzled
// LDS for A and B, gload_lds staging) with MFMA shape 32x32x16 (8.07 cyc per
// 32k FLOP vs 9.7 for 2x 16x16x32: -17% matrix-pipe floor, half the MFMA
// instruction count). Swizzle (T2), counted vmcnt (T4), setprio (T5), XCD (T1).

#define M_DIM 8192
#define N_DIM 4096
#define K_DIM 4096
#define BM 256
#define BN 256
#define BK 64
#define NT (K_DIM / BK)          // 64

typedef __attribute__((ext_vector_type(4)))  float    f32x4;
typedef __attribute__((ext_vector_type(16))) float    f32x16;
typedef __attribute__((ext_vector_type(4)))  int      i32x4;
typedef __attribute__((ext_vector_type(2)))  uint32_t u32x2;
typedef __attribute__((ext_vector_type(4)))  uint32_t u32x4;
typedef __attribute__((ext_vector_type(8)))  short    bf16x8;
typedef uint32_t u32;

__device__ __forceinline__ u32 fbits(float f) { return __builtin_bit_cast(u32, f); }
// two f32 -> two bf16 by truncation (1 v_perm_b32); exact for int8-valued floats.
__device__ __forceinline__ u32 pack_bf16_trunc(float lo, float hi) {
    return __builtin_amdgcn_perm(fbits(hi), fbits(lo), 0x07060302u);
}
// LDS byte address for logical (row, byte-col) in a [256][128B] tile (fallback).
__device__ __forceinline__ int swzb(int row, int bytecol) {
    return row * 128 + (bytecol ^ ((row & 7) << 4));
}

// global_load_lds, 16B per lane. LDS dst is wave-uniform; HW writes dst+lane*16.
__device__ __forceinline__ void gload_lds16(const void* g, void* s) {
    __builtin_amdgcn_global_load_lds(
        (const __attribute__((address_space(1))) void*)(uintptr_t)g,
        (__attribute__((address_space(3))) void*)(u32)(uintptr_t)s, 16, 0, 0);
}

#define WAIT_VM4()   do { asm volatile("s_waitcnt vmcnt(4)" ::: "memory");   \
                          __builtin_amdgcn_sched_barrier(0); } while (0)
#define WAIT_VM0()   do { asm volatile("s_waitcnt vmcnt(0)" ::: "memory");   \
                          __builtin_amdgcn_sched_barrier(0); } while (0)
#define BARRIER()    do { __builtin_amdgcn_s_barrier();                      \
                          __builtin_amdgcn_sched_barrier(0); } while (0)

// ---- pre-convert: W int32 -> bf16 (same layout) ----
__global__ __launch_bounds__(256)
void qlin_convert_w(const int* __restrict__ Wq, short* __restrict__ Wb)
{
    const size_t i = (size_t)blockIdx.x * 256 + threadIdx.x;   // 8 elts/thread
    i32x4 w0 = ((const i32x4*)Wq)[2 * i];
    i32x4 w1 = ((const i32x4*)Wq)[2 * i + 1];
    u32x4 q;
    q[0] = pack_bf16_trunc((float)w0[0], (float)w0[1]);
    q[1] = pack_bf16_trunc((float)w0[2], (float)w0[3]);
    q[2] = pack_bf16_trunc((float)w1[0], (float)w1[1]);
    q[3] = pack_bf16_trunc((float)w1[2], (float)w1[3]);
    ((u32x4*)Wb)[i] = q;
}

// ---- pre-convert: X f32 -> bf16 ----
__global__ __launch_bounds__(256)
void qlin_convert_x(const float* __restrict__ X, short* __restrict__ Xb)
{
    const size_t i = (size_t)blockIdx.x * 256 + threadIdx.x;   // 8 elts/thread
    f32x4 a = ((const f32x4*)X)[2 * i];
    f32x4 b = ((const f32x4*)X)[2 * i + 1];
    u32x4 q;
    q[0] = pack_bf16_trunc(a[0], a[1]);
    q[1] = pack_bf16_trunc(a[2], a[3]);
    q[2] = pack_bf16_trunc(b[0], b[1]);
    q[3] = pack_bf16_trunc(b[2], b[3]);
    ((u32x4*)Xb)[i] = q;
}

// ===================== main pipelined GEMM (bf16 inputs) =====================
// LDS per operand: [2 dbuf][2 half][128 rows][128 B]. Logical (row,bytecol) at
// physical row*128 + (bytecol ^ ((row&7)<<4)); global source pre-swizzled with
// the same XOR so the linear DMA write lands swizzled (rule 21).
// MFMA 32x32x16: A-frag lane l: row=l&31, k=(l>>5)*8+e (16B at byte col
// ks16*32 + (l>>5)*16); B symmetric. C/D: col=lane&31,
// row=(reg&3)+8*(reg>>2)+4*(lane>>5), reg in [0,16).
__global__ __launch_bounds__(512, 2)
void qlin_gemm_p(const short* __restrict__ A, const short* __restrict__ B,
                 const float* __restrict__ scale_p, float* __restrict__ C)
{
    __shared__ __align__(16) char As[2][2][128 * 128];   // 64 KiB
    __shared__ __align__(16) char Bs[2][2][128 * 128];   // 64 KiB

    const int tid = threadIdx.x;
    // XCD swizzle: nwg = 512, divisible by 8 -> bijective
    const int nwg = (M_DIM / BM) * (N_DIM / BN);   // 512
    const int cpx = nwg / 8;
    const int bid = ((int)blockIdx.x % 8) * cpx + (int)blockIdx.x / 8;
    const int tileM = (bid / (N_DIM / BN)) * BM;
    const int tileN = (bid % (N_DIM / BN)) * BN;

    const int lane = tid & 63;
    const int wid  = tid >> 6;       // 0..7
    const int wr   = wid >> 2;       // 0..1  (wave covers 128 M-rows = A half wr)
    const int wc   = wid & 3;        // 0..3  (wave covers 64 N-cols)
    const int l31  = lane & 31;
    const int lh   = lane >> 5;      // 0..1

    // staging source addressing (per lane): 8 rows x 128B per wave-issue
    const int srow = lane >> 3;                    // 0..7
    const int scol = ((lane & 7) ^ srow) << 4;     // inverse-swizzled byte col
    const char* Ag = (const char*)A;
    const char* Bg = (const char*)B;

    // stage one half-tile (2 x global_load_lds per thread)
    auto stageA = [&](int buf, int h, int kt) {
#pragma unroll
        for (int j = 0; j < 2; ++j) {
            const int seg = wid * 2 + j;           // 0..15
            const char* src = Ag + (size_t)(tileM + h * 128 + seg * 8 + srow) * (K_DIM * 2)
                                 + kt * (BK * 2) + scol;
            gload_lds16(src, &As[buf][h][seg * 1024]);
        }
    };
    auto stageB = [&](int buf, int h, int kt) {
#pragma unroll
        for (int j = 0; j < 2; ++j) {
            const int seg = wid * 2 + j;
            const char* src = Bg + (size_t)(tileN + h * 128 + seg * 8 + srow) * (K_DIM * 2)
                                 + kt * (BK * 2) + scol;
            gload_lds16(src, &Bs[buf][h][seg * 1024]);
        }
    };

    // ---- fragments ----
    f32x16 acc[4][2] = {};           // 4 M-blocks x 2 N-blocks of 32x32
    bf16x8 amA[2][4], amB[2][4];     // A frags: [m-block][ks16]
    bf16x8 bn[2][4];                 // B frags: [n-block][ks16]

    auto swzh = [](int row, int bc) { return row * 128 + (bc ^ ((row & 7) << 4)); };
    auto ldA32 = [&](int buf, int mlo, bf16x8 (&am)[2][4]) {
#pragma unroll
        for (int mi = 0; mi < 2; ++mi) {
            const int row = (mlo + mi) * 32 + l31;              // 0..127 in half wr
#pragma unroll
            for (int ks = 0; ks < 4; ++ks)
                am[mi][ks] = *(const bf16x8*)&As[buf][wr][swzh(row, ks * 32 + lh * 16)];
        }
    };
    auto ldB32 = [&](int buf) {
#pragma unroll
        for (int ni = 0; ni < 2; ++ni) {
            const int r = wc * 64 + ni * 32 + l31;              // 0..255
#pragma unroll
            for (int ks = 0; ks < 4; ++ks)
                bn[ni][ks] = *(const bf16x8*)&Bs[buf][r >> 7][swzh(r & 127, ks * 32 + lh * 16)];
        }
    };
    // 16 MFMA: (mlo..mlo+1) x both n-blocks x 4 ks16 steps
    auto cluster = [&](int mlo, bf16x8 (&am)[2][4]) {
        __builtin_amdgcn_s_setprio(1);
#pragma unroll
        for (int ks = 0; ks < 4; ++ks)
#pragma unroll
            for (int mi = 0; mi < 2; ++mi)
#pragma unroll
                for (int ni = 0; ni < 2; ++ni)
                    acc[mlo + mi][ni] = __builtin_amdgcn_mfma_f32_32x32x16_bf16(
                        am[mi][ks], bn[ni][ks], acc[mlo + mi][ni], 0, 0, 0);
        __builtin_amdgcn_s_setprio(0);
    };

    // ---- prologue: tile0 fully + tile1 B-halves; keep 4 loads in flight ----
    stageA(0, 0, 0); stageA(0, 1, 0);
    stageB(0, 0, 0); stageB(0, 1, 0);
    stageB(1, 0, 1); stageB(1, 1, 1);
    WAIT_VM4();          // tile0's 8 loads landed; tile1's 4 B loads in flight
    BARRIER();

    // ---- main loop: R2 ledger, 32x32 compute ----
    // Entry invariant tile t (buf c=t&1): A(t),B(t) in buf c; B(t+1)[4] in
    // flight to buf c^1. Top: stageA(t+1) into c^1 (region free since t-1's
    // readers retired before last barrier). cluster(0) consumes ALL bn frags
    // -> by S1 every lane's B data is in regs -> stageB(cur, t+2) safe.
    // amB reads issued pre-S1, consumed post-S1; As[cur] not rewritten until
    // t+2's stageA (after t+1's S2). vmcnt at S2: outstanding = B(t+1)[4] +
    // A(t+1)[4] + B(t+2)[4] = 12 -> wait(4) leaves B(t+2), drains t+1.
#pragma unroll 1
    for (int kt = 0; kt < NT; ++kt) {
        const int cur = kt & 1, nxt = cur ^ 1;

        if (kt + 1 < NT) { stageA(nxt, 0, kt + 1); stageA(nxt, 1, kt + 1); }

        ldA32(cur, 0, amA);          // 8 ds_reads
        ldB32(cur);                  // 8 ds_reads
        cluster(0, amA);             // 16 MFMA (all bn consumed)
        ldA32(cur, 2, amB);          // 8 ds_reads, consumed after S1

        BARRIER();                   // S1
        if (kt + 2 < NT) { stageB(cur, 0, kt + 2); stageB(cur, 1, kt + 2); }

        cluster(2, amB);             // 16 MFMA

        if (kt + 2 < NT)      { WAIT_VM4(); }   // t+1 landed; B(t+2) in flight
        else if (kt + 1 < NT) { WAIT_VM0(); }   // tail: drain last tile
        BARRIER();                   // S2
    }

    // ---- epilogue: 32x32 C/D layout ----
    const float scl = scale_p[0];
#pragma unroll
    for (int mi = 0; mi < 4; ++mi)
#pragma unroll
        for (int ni = 0; ni < 2; ++ni) {
            const int gcol = tileN + wc * 64 + ni * 32 + l31;
#pragma unroll
            for (int r = 0; r < 16; ++r) {
                const int grow = tileM + wr * 128 + mi * 32
                               + (r & 3) + 8 * (r >> 2) + 4 * lh;
                C[(size_t)grow * N_DIM + gcol] = acc[mi][ni][r] * scl;
            }
        }
}

// ===================== fallback (no workspace): reg-staged kernel ============
#define TILE_BYTES (BM * BK * 2)
__global__ __launch_bounds__(512, 2)
void qlin_gemm8(const void* __restrict__ Asrc, const void* __restrict__ Bsrc,
                const float* __restrict__ scale_p, float* __restrict__ C)
{
    __shared__ char As[2 * TILE_BYTES];
    __shared__ char Bs[2 * TILE_BYTES];

    const int tid = threadIdx.x;
    const int nwg = (M_DIM / BM) * (N_DIM / BN);
    const int cpx = nwg / 8;
    const int bid = ((int)blockIdx.x % 8) * cpx + (int)blockIdx.x / 8;
    const int tileM = (bid / (N_DIM / BN)) * BM;
    const int tileN = (bid % (N_DIM / BN)) * BN;

    const int lane = tid & 63;
    const int wid  = tid >> 6;
    const int wr   = wid >> 2;
    const int wc   = wid & 3;
    const int lr   = lane & 15;
    const int lq   = lane >> 4;

    f32x4  aF[8]; i32x4 wF[8];

    const float* ag0 = (const float*)Asrc + (size_t)(tileM + (tid >> 4)) * K_DIM + (tid & 15) * 4;
    const int*   bg0 = (const int*)Bsrc  + (size_t)(tileN + (tid >> 4)) * K_DIM + (tid & 15) * 4;

    auto stage_load = [&](int kt) {
#pragma unroll
        for (int i = 0; i < 8; ++i)
            aF[i] = *(const f32x4*)(ag0 + (size_t)(32 * i) * K_DIM + kt * BK);
#pragma unroll
        for (int i = 0; i < 8; ++i)
            wF[i] = *(const i32x4*)(bg0 + (size_t)(32 * i) * K_DIM + kt * BK);
    };
    auto stage_writeA = [&](int nxt) {
        char* dst = As + nxt * TILE_BYTES;
#pragma unroll
        for (int i = 0; i < 8; ++i) {
            u32x2 p;
            p[0] = pack_bf16_trunc(aF[i][0], aF[i][1]);
            p[1] = pack_bf16_trunc(aF[i][2], aF[i][3]);
            *(u32x2*)(dst + swzb((tid >> 4) + 32 * i, (tid & 15) * 8)) = p;
        }
    };
    auto stage_writeB = [&](int nxt) {
        char* dst = Bs + nxt * TILE_BYTES;
#pragma unroll
        for (int i = 0; i < 8; ++i) {
            u32x2 p;
            p[0] = pack_bf16_trunc((float)wF[i][0], (float)wF[i][1]);
            p[1] = pack_bf16_trunc((float)wF[i][2], (float)wF[i][3]);
            *(u32x2*)(dst + swzb((tid >> 4) + 32 * i, (tid & 15) * 8)) = p;
        }
    };

    f32x4  acc[8][4] = {};
    bf16x8 afr[4][2], bfr[2][2];

    auto ldA = [&](const char* buf, int mb) {
#pragma unroll
        for (int m = 0; m < 4; ++m) {
            const int row = wr * 128 + (mb + m) * 16 + lr;
#pragma unroll
            for (int ks = 0; ks < 2; ++ks)
                afr[m][ks] = *(const bf16x8*)(buf + swzb(row, ks * 64 + lq * 16));
        }
    };
    auto ldB = [&](const char* buf, int nb) {
#pragma unroll
        for (int n = 0; n < 2; ++n) {
            const int row = wc * 64 + (nb + n) * 16 + lr;
#pragma unroll
            for (int ks = 0; ks < 2; ++ks)
                bfr[n][ks] = *(const bf16x8*)(buf + swzb(row, ks * 64 + lq * 16));
        }
    };
    auto quad = [&](int mb, int nb) {
        __builtin_amdgcn_s_setprio(1);
#pragma unroll
        for (int m = 0; m < 4; ++m)
#pragma unroll
            for (int n = 0; n < 2; ++n)
#pragma unroll
                for (int ks = 0; ks < 2; ++ks)
                    acc[mb + m][nb + n] = __builtin_amdgcn_mfma_f32_16x16x32_bf16(
                        afr[m][ks], bfr[n][ks], acc[mb + m][nb + n], 0, 0, 0);
        __builtin_amdgcn_s_setprio(0);
    };

    stage_load(0);
    stage_writeA(0);
    stage_writeB(0);
    __syncthreads();

#pragma unroll 1
    for (int kt = 0; kt < NT; ++kt) {
        const int cur = kt & 1, nxt = cur ^ 1;
        const bool more = (kt + 1) < NT;
        const char* Ab = As + cur * TILE_BYTES;
        const char* Bb = Bs + cur * TILE_BYTES;

        if (more) stage_load(kt + 1);

        ldA(Ab, 0); ldB(Bb, 0); quad(0, 0);
        ldB(Bb, 2);             quad(0, 2);
        ldA(Ab, 4);
        if (more) stage_writeA(nxt);
        quad(4, 2);
        ldB(Bb, 0);
        if (more) stage_writeB(nxt);
        quad(4, 0);

        __syncthreads();
    }

    const float scl = scale_p[0];
#pragma unroll
    for (int m = 0; m < 8; ++m) {
        const int gm0 = tileM + wr * 128 + m * 16 + lq * 4;
#pragma unroll
        for (int n = 0; n < 4; ++n) {
            const int gn = tileN + wc * 64 + n * 16 + lr;
            float* cp = C + (size_t)gm0 * N_DIM + gn;
#pragma unroll
            for (int r = 0; r < 4; ++r)
                cp[(size_t)r * N_DIM] = acc[m][n][r] * scl;
        }
    }
}

extern "C" void kernel_launch(void* const* d_in, const int* in_sizes, int n_in,
                              void* d_out, int out_size, void* d_ws, size_t ws_size,
                              hipStream_t stream)
{
    (void)in_sizes; (void)n_in; (void)out_size;
    const float* X     = (const float*)d_in[0];
    const int*   Wq    = (const int*)d_in[1];      // int8-valued, delivered as int32
    const float* scale = (const float*)d_in[2];
    float* C = (float*)d_out;

    const dim3 gblock(256);
    const dim3 ggrid((M_DIM / BM) * (N_DIM / BN));  // 512
    const size_t xbytes = (size_t)M_DIM * K_DIM * sizeof(short);   // 64 MiB
    const size_t wbytes = (size_t)N_DIM * K_DIM * sizeof(short);   // 32 MiB

    if (ws_size >= xbytes + wbytes) {
        short* Xb = (short*)d_ws;
        short* Wb = (short*)((char*)d_ws + xbytes);
        qlin_convert_x<<<dim3((size_t)M_DIM * K_DIM / (8 * 256)), gblock, 0, stream>>>(X, Xb);
        qlin_convert_w<<<dim3((size_t)N_DIM * K_DIM / (8 * 256)), gblock, 0, stream>>>(Wq, Wb);
        qlin_gemm_p<<<ggrid, dim3(512), 0, stream>>>(Xb, Wb, scale, C);
    } else {
        qlin_gemm8<<<ggrid, dim3(512), 0, stream>>>(X, Wq, scale, C);
    }
}

// Round 7
// 292.032 us; speedup vs baseline: 1.6021x; 1.0374x over previous
//
#include <hip/hip_runtime.h>
#include <hip/hip_bf16.h>
#include <stdint.h>

// QuantizedCpuLinear: y = scale * (x @ wq^T)
// x: f32 [8192,4096]; wq int8-valued delivered as int32 [4096,4096] (K contig);
// out f32 [8192,4096]. bf16 MFMA GEMM, 256x256 tile, 8 waves, 16x16x32 MFMA.
// R7: BK=32 -> 16KB LDS tiles -> 64 KiB total -> TWO blocks resident per CU
// (4 waves/SIMD from independent blocks). Intra-block schedule = R2's proven
// 2-barrier + counted-vmcnt ledger (scaled). Cross-block anti-phasing overlaps
// the MFMA pipe of one block with the LDS/stage phase of the other (m114).
// Swizzle for 64B rows: chunk H of row R at slot H ^ ((R>>1)&3); DMA source
// pre-swizzled with the same involution (rule 21). T1/T2/T4/T5 retained.

#define M_DIM 8192
#define N_DIM 4096
#define K_DIM 4096
#define BM 256
#define BN 256
#define BK 64                    // fallback kernel only
#define NT (K_DIM / BK)          // 64 (fallback)
#define BKP 32                   // pipelined kernel K-step
#define NTP (K_DIM / BKP)        // 128

typedef __attribute__((ext_vector_type(4))) float    f32x4;
typedef __attribute__((ext_vector_type(4))) int      i32x4;
typedef __attribute__((ext_vector_type(2))) uint32_t u32x2;
typedef __attribute__((ext_vector_type(4))) uint32_t u32x4;
typedef __attribute__((ext_vector_type(8))) short    bf16x8;
typedef uint32_t u32;

__device__ __forceinline__ u32 fbits(float f) { return __builtin_bit_cast(u32, f); }
// two f32 -> two bf16 by truncation (1 v_perm_b32); exact for int8-valued floats.
__device__ __forceinline__ u32 pack_bf16_trunc(float lo, float hi) {
    return __builtin_amdgcn_perm(fbits(hi), fbits(lo), 0x07060302u);
}
// LDS byte address for logical (row, byte-col) in a [256][128B] tile (fallback).
__device__ __forceinline__ int swzb(int row, int bytecol) {
    return row * 128 + (bytecol ^ ((row & 7) << 4));
}

// global_load_lds, 16B per lane. LDS dst is wave-uniform; HW writes dst+lane*16.
__device__ __forceinline__ void gload_lds16(const void* g, void* s) {
    __builtin_amdgcn_global_load_lds(
        (const __attribute__((address_space(1))) void*)(uintptr_t)g,
        (__attribute__((address_space(3))) void*)(u32)(uintptr_t)s, 16, 0, 0);
}

#define WAIT_VM2()   do { asm volatile("s_waitcnt vmcnt(2)" ::: "memory");   \
                          __builtin_amdgcn_sched_barrier(0); } while (0)
#define WAIT_VM0()   do { asm volatile("s_waitcnt vmcnt(0)" ::: "memory");   \
                          __builtin_amdgcn_sched_barrier(0); } while (0)
#define BARRIER()    do { __builtin_amdgcn_s_barrier();                      \
                          __builtin_amdgcn_sched_barrier(0); } while (0)

// ---- pre-convert: W int32 -> bf16 (same layout) ----
__global__ __launch_bounds__(256)
void qlin_convert_w(const int* __restrict__ Wq, short* __restrict__ Wb)
{
    const size_t i = (size_t)blockIdx.x * 256 + threadIdx.x;   // 8 elts/thread
    i32x4 w0 = ((const i32x4*)Wq)[2 * i];
    i32x4 w1 = ((const i32x4*)Wq)[2 * i + 1];
    u32x4 q;
    q[0] = pack_bf16_trunc((float)w0[0], (float)w0[1]);
    q[1] = pack_bf16_trunc((float)w0[2], (float)w0[3]);
    q[2] = pack_bf16_trunc((float)w1[0], (float)w1[1]);
    q[3] = pack_bf16_trunc((float)w1[2], (float)w1[3]);
    ((u32x4*)Wb)[i] = q;
}

// ---- pre-convert: X f32 -> bf16 ----
__global__ __launch_bounds__(256)
void qlin_convert_x(const float* __restrict__ X, short* __restrict__ Xb)
{
    const size_t i = (size_t)blockIdx.x * 256 + threadIdx.x;   // 8 elts/thread
    f32x4 a = ((const f32x4*)X)[2 * i];
    f32x4 b = ((const f32x4*)X)[2 * i + 1];
    u32x4 q;
    q[0] = pack_bf16_trunc(a[0], a[1]);
    q[1] = pack_bf16_trunc(a[2], a[3]);
    q[2] = pack_bf16_trunc(b[0], b[1]);
    q[3] = pack_bf16_trunc(b[2], b[3]);
    ((u32x4*)Xb)[i] = q;
}

// ===================== main pipelined GEMM (bf16 inputs) =====================
// LDS per operand: [2 dbuf][256 rows][64 B] = 16 KiB/buf; 64 KiB total.
// Storage swizzle: 16B chunk H (0..3) of row R at byte R*64 + (H^((R>>1)&3))*16.
// DMA writes linearly (lane i -> row seg*16+(i>>2), slot i&3), so the global
// source column is pre-swizzled: H = (i&3) ^ ((i>>3)&3) (involution, rule 21).
// Read: frag chunk lq of row R at slot lq ^ ((R>>1)&3) -> thread-constant
// offset; per-instruction bank pattern matches R2's verified 0-conflict shape.
__global__ __launch_bounds__(512, 2)
void qlin_gemm_p(const short* __restrict__ A, const short* __restrict__ B,
                 const float* __restrict__ scale_p, float* __restrict__ C)
{
    __shared__ __align__(16) char As[2][256 * 64];   // 32 KiB
    __shared__ __align__(16) char Bs[2][256 * 64];   // 32 KiB

    const int tid = threadIdx.x;
    // XCD swizzle: nwg = 512, divisible by 8 -> bijective
    const int nwg = (M_DIM / BM) * (N_DIM / BN);   // 512
    const int cpx = nwg / 8;
    const int bid = ((int)blockIdx.x % 8) * cpx + (int)blockIdx.x / 8;
    const int tileM = (bid / (N_DIM / BN)) * BM;
    const int tileN = (bid % (N_DIM / BN)) * BN;

    const int lane = tid & 63;
    const int wid  = tid >> 6;       // 0..7
    const int wr   = wid >> 2;       // 0..1  (wave covers 128 M-rows)
    const int wc   = wid & 3;        // 0..3  (wave covers 64 N-cols)
    const int lr   = lane & 15;
    const int lq   = lane >> 4;

    // staging: lane i covers row seg*16 + (i>>2), chunk H = (i&3)^((i>>3)&3)
    const int scol = (((lane & 3) ^ ((lane >> 3) & 3)) << 4);
    const char* Ag = (const char*)A;
    const char* Bg = (const char*)B;

    // stage one 16KB tile: 2 x global_load_lds per thread (8KB per wave-issue)
    auto stageA = [&](int buf, int kt) {
#pragma unroll
        for (int j = 0; j < 2; ++j) {
            const int seg = wid * 2 + j;           // 0..15 -> rows seg*16..+15
            const char* src = Ag + (size_t)(tileM + seg * 16 + (lane >> 2)) * (K_DIM * 2)
                                 + kt * (BKP * 2) + scol;
            gload_lds16(src, &As[buf][seg * 1024]);
        }
    };
    auto stageB = [&](int buf, int kt) {
#pragma unroll
        for (int j = 0; j < 2; ++j) {
            const int seg = wid * 2 + j;
            const char* src = Bg + (size_t)(tileN + seg * 16 + (lane >> 2)) * (K_DIM * 2)
                                 + kt * (BKP * 2) + scol;
            gload_lds16(src, &Bs[buf][seg * 1024]);
        }
    };

    // ---- fragments ----
    f32x4  acc[8][4] = {};
    bf16x8 afr[8], bn[4];

    // read slot offset: lq ^ ((row>>1)&3); all row offsets are multiples of 16
    // so (row>>1)&3 == (lr>>1)&3 -> thread-constant byte offset within the row.
    const int roff = ((lq ^ ((lr >> 1) & 3)) << 4);

    auto ldA1 = [&](int buf, int m) {
        const int row = wr * 128 + m * 16 + lr;
        afr[m] = *(const bf16x8*)&As[buf][row * 64 + roff];
    };
    auto ldB4 = [&](int buf) {
#pragma unroll
        for (int nb = 0; nb < 4; ++nb) {
            const int row = wc * 64 + nb * 16 + lr;
            bn[nb] = *(const bf16x8*)&Bs[buf][row * 64 + roff];
        }
    };
    // 16 MFMA: (mlo..mlo+3) x all 4 n-blocks, K=32 in one shot
    auto cluster = [&](int mlo) {
        __builtin_amdgcn_s_setprio(1);
#pragma unroll
        for (int m = 0; m < 4; ++m)
#pragma unroll
            for (int n = 0; n < 4; ++n)
                acc[mlo + m][n] = __builtin_amdgcn_mfma_f32_16x16x32_bf16(
                    afr[mlo + m], bn[n], acc[mlo + m][n], 0, 0, 0);
        __builtin_amdgcn_s_setprio(0);
    };

    // ---- prologue: tile0 A+B; tile1 B; keep 2 loads in flight ----
    stageA(0, 0); stageB(0, 0);      // 4 issues
    stageB(1, 1);                    // 2 issues
    WAIT_VM2();        // A(0),B(0) landed; B(1) in flight
    BARRIER();

    // ---- main loop: R2 ledger scaled to BKP=32 ----
    // Entry invariant tile t (buf c=t&1): A(t),B(t) in buf c; B(t+1)[2] in
    // flight to buf c^1. Top: stageA(t+1) into c^1 (its readers retired before
    // t-1's S2). cluster(0) consumes ALL bn -> S1 -> stageB(cur, t+2) safe.
    // afr[4..7] read pre-S1 from As[cur], consumed post-S1; As[cur] rewritten
    // only at t+1's top (after S2). vmcnt at S2: FIFO = B(t+1)[2] + A(t+1)[2] +
    // B(t+2)[2] = 6 -> wait(2) drains t+1 (issued >=1 tile ago), leaves B(t+2).
#pragma unroll 1
    for (int kt = 0; kt < NTP; ++kt) {
        const int cur = kt & 1, nxt = cur ^ 1;

        if (kt + 1 < NTP) stageA(nxt, kt + 1);   // 2 issues

        ldB4(cur);                               // 4 ds_reads
        ldA1(cur, 0); ldA1(cur, 1); ldA1(cur, 2); ldA1(cur, 3);
        cluster(0);                              // 16 MFMA (all bn consumed)
        ldA1(cur, 4); ldA1(cur, 5); ldA1(cur, 6); ldA1(cur, 7);

        BARRIER();                               // S1
        if (kt + 2 < NTP) stageB(cur, kt + 2);   // 2 issues

        cluster(4);                              // 16 MFMA

        if (kt + 2 < NTP)      { WAIT_VM2(); }   // t+1 landed; B(t+2) in flight
        else if (kt + 1 < NTP) { WAIT_VM0(); }   // tail: drain last tile
        BARRIER();                               // S2
    }

    // ---- epilogue: C/D layout col=lane&15, row=(lane>>4)*4+reg ----
    const float scl = scale_p[0];
#pragma unroll
    for (int m = 0; m < 8; ++m) {
        const int gm0 = tileM + wr * 128 + m * 16 + lq * 4;
#pragma unroll
        for (int n = 0; n < 4; ++n) {
            const int gn = tileN + wc * 64 + n * 16 + lr;
            float* cp = C + (size_t)gm0 * N_DIM + gn;
#pragma unroll
            for (int r = 0; r < 4; ++r)
                cp[(size_t)r * N_DIM] = acc[m][n][r] * scl;
        }
    }
}

// ===================== fallback (no workspace): reg-staged kernel ============
#define TILE_BYTES (BM * BK * 2)
__global__ __launch_bounds__(512, 2)
void qlin_gemm8(const void* __restrict__ Asrc, const void* __restrict__ Bsrc,
                const float* __restrict__ scale_p, float* __restrict__ C)
{
    __shared__ char As[2 * TILE_BYTES];
    __shared__ char Bs[2 * TILE_BYTES];

    const int tid = threadIdx.x;
    const int nwg = (M_DIM / BM) * (N_DIM / BN);
    const int cpx = nwg / 8;
    const int bid = ((int)blockIdx.x % 8) * cpx + (int)blockIdx.x / 8;
    const int tileM = (bid / (N_DIM / BN)) * BM;
    const int tileN = (bid % (N_DIM / BN)) * BN;

    const int lane = tid & 63;
    const int wid  = tid >> 6;
    const int wr   = wid >> 2;
    const int wc   = wid & 3;
    const int lr   = lane & 15;
    const int lq   = lane >> 4;

    f32x4  aF[8]; i32x4 wF[8];

    const float* ag0 = (const float*)Asrc + (size_t)(tileM + (tid >> 4)) * K_DIM + (tid & 15) * 4;
    const int*   bg0 = (const int*)Bsrc  + (size_t)(tileN + (tid >> 4)) * K_DIM + (tid & 15) * 4;

    auto stage_load = [&](int kt) {
#pragma unroll
        for (int i = 0; i < 8; ++i)
            aF[i] = *(const f32x4*)(ag0 + (size_t)(32 * i) * K_DIM + kt * BK);
#pragma unroll
        for (int i = 0; i < 8; ++i)
            wF[i] = *(const i32x4*)(bg0 + (size_t)(32 * i) * K_DIM + kt * BK);
    };
    auto stage_writeA = [&](int nxt) {
        char* dst = As + nxt * TILE_BYTES;
#pragma unroll
        for (int i = 0; i < 8; ++i) {
            u32x2 p;
            p[0] = pack_bf16_trunc(aF[i][0], aF[i][1]);
            p[1] = pack_bf16_trunc(aF[i][2], aF[i][3]);
            *(u32x2*)(dst + swzb((tid >> 4) + 32 * i, (tid & 15) * 8)) = p;
        }
    };
    auto stage_writeB = [&](int nxt) {
        char* dst = Bs + nxt * TILE_BYTES;
#pragma unroll
        for (int i = 0; i < 8; ++i) {
            u32x2 p;
            p[0] = pack_bf16_trunc((float)wF[i][0], (float)wF[i][1]);
            p[1] = pack_bf16_trunc((float)wF[i][2], (float)wF[i][3]);
            *(u32x2*)(dst + swzb((tid >> 4) + 32 * i, (tid & 15) * 8)) = p;
        }
    };

    f32x4  acc[8][4] = {};
    bf16x8 afr[4][2], bfr[2][2];

    auto ldA = [&](const char* buf, int mb) {
#pragma unroll
        for (int m = 0; m < 4; ++m) {
            const int row = wr * 128 + (mb + m) * 16 + lr;
#pragma unroll
            for (int ks = 0; ks < 2; ++ks)
                afr[m][ks] = *(const bf16x8*)(buf + swzb(row, ks * 64 + lq * 16));
        }
    };
    auto ldB = [&](const char* buf, int nb) {
#pragma unroll
        for (int n = 0; n < 2; ++n) {
            const int row = wc * 64 + (nb + n) * 16 + lr;
#pragma unroll
            for (int ks = 0; ks < 2; ++ks)
                bfr[n][ks] = *(const bf16x8*)(buf + swzb(row, ks * 64 + lq * 16));
        }
    };
    auto quad = [&](int mb, int nb) {
        __builtin_amdgcn_s_setprio(1);
#pragma unroll
        for (int m = 0; m < 4; ++m)
#pragma unroll
            for (int n = 0; n < 2; ++n)
#pragma unroll
                for (int ks = 0; ks < 2; ++ks)
                    acc[mb + m][nb + n] = __builtin_amdgcn_mfma_f32_16x16x32_bf16(
                        afr[m][ks], bfr[n][ks], acc[mb + m][nb + n], 0, 0, 0);
        __builtin_amdgcn_s_setprio(0);
    };

    stage_load(0);
    stage_writeA(0);
    stage_writeB(0);
    __syncthreads();

#pragma unroll 1
    for (int kt = 0; kt < NT; ++kt) {
        const int cur = kt & 1, nxt = cur ^ 1;
        const bool more = (kt + 1) < NT;
        const char* Ab = As + cur * TILE_BYTES;
        const char* Bb = Bs + cur * TILE_BYTES;

        if (more) stage_load(kt + 1);

        ldA(Ab, 0); ldB(Bb, 0); quad(0, 0);
        ldB(Bb, 2);             quad(0, 2);
        ldA(Ab, 4);
        if (more) stage_writeA(nxt);
        quad(4, 2);
        ldB(Bb, 0);
        if (more) stage_writeB(nxt);
        quad(4, 0);

        __syncthreads();
    }

    const float scl = scale_p[0];
#pragma unroll
    for (int m = 0; m < 8; ++m) {
        const int gm0 = tileM + wr * 128 + m * 16 + lq * 4;
#pragma unroll
        for (int n = 0; n < 4; ++n) {
            const int gn = tileN + wc * 64 + n * 16 + lr;
            float* cp = C + (size_t)gm0 * N_DIM + gn;
#pragma unroll
            for (int r = 0; r < 4; ++r)
                cp[(size_t)r * N_DIM] = acc[m][n][r] * scl;
        }
    }
}

extern "C" void kernel_launch(void* const* d_in, const int* in_sizes, int n_in,
                              void* d_out, int out_size, void* d_ws, size_t ws_size,
                              hipStream_t stream)
{
    (void)in_sizes; (void)n_in; (void)out_size;
    const float* X     = (const float*)d_in[0];
    const int*   Wq    = (const int*)d_in[1];      // int8-valued, delivered as int32
    const float* scale = (const float*)d_in[2];
    float* C = (float*)d_out;

    const dim3 gblock(256);
    const dim3 ggrid((M_DIM / BM) * (N_DIM / BN));  // 512
    const size_t xbytes = (size_t)M_DIM * K_DIM * sizeof(short);   // 64 MiB
    const size_t wbytes = (size_t)N_DIM * K_DIM * sizeof(short);   // 32 MiB

    if (ws_size >= xbytes + wbytes) {
        short* Xb = (short*)d_ws;
        short* Wb = (short*)((char*)d_ws + xbytes);
        qlin_convert_x<<<dim3((size_t)M_DIM * K_DIM / (8 * 256)), gblock, 0, stream>>>(X, Xb);
        qlin_convert_w<<<dim3((size_t)N_DIM * K_DIM / (8 * 256)), gblock, 0, stream>>>(Wq, Wb);
        qlin_gemm_p<<<ggrid, dim3(512), 0, stream>>>(Xb, Wb, scale, C);
    } else {
        qlin_gemm8<<<ggrid, dim3(512), 0, stream>>>(X, Wq, scale, C);
    }
}

// Round 8
// 287.013 us; speedup vs baseline: 1.6301x; 1.0175x over previous
//
#include <hip/hip_runtime.h>
#include <hip/hip_bf16.h>
#include <stdint.h>

// QuantizedCpuLinear: y = scale * (x @ wq^T)
// x: f32 [8192,4096]; wq int8-valued delivered as int32 [4096,4096] (K contig);
// out f32 [8192,4096]. bf16 MFMA GEMM, 256x256 tile, 8 waves, 16x16x32 MFMA.
// R8: BK=32 + THREE LDS buffers (96 KiB) -> stage tile t+2 during tile t into
// a buffer nobody reads -> zero mid-tile barriers. One s_barrier + one
// vmcnt(4) per K-tile; the waited loads are 2 tiles old (never stalls) and the
// ledger FORMALLY guarantees tile t+1 is resident before any tile-t+1 read.
// Waves drift freely within a tile -> ds_read bursts anti-phase against other
// waves' MFMA clusters. Swizzle (T2, R7's measured-clean 64B-row form),
// counted vmcnt (T4), setprio (T5), XCD swz (T1).

#define M_DIM 8192
#define N_DIM 4096
#define K_DIM 4096
#define BM 256
#define BN 256
#define BK 64                    // fallback kernel only
#define NT (K_DIM / BK)          // 64 (fallback)
#define BKP 32                   // pipelined kernel K-step
#define NTP (K_DIM / BKP)        // 128

typedef __attribute__((ext_vector_type(4))) float    f32x4;
typedef __attribute__((ext_vector_type(4))) int      i32x4;
typedef __attribute__((ext_vector_type(2))) uint32_t u32x2;
typedef __attribute__((ext_vector_type(4))) uint32_t u32x4;
typedef __attribute__((ext_vector_type(8))) short    bf16x8;
typedef uint32_t u32;

__device__ __forceinline__ u32 fbits(float f) { return __builtin_bit_cast(u32, f); }
// two f32 -> two bf16 by truncation (1 v_perm_b32); exact for int8-valued floats.
__device__ __forceinline__ u32 pack_bf16_trunc(float lo, float hi) {
    return __builtin_amdgcn_perm(fbits(hi), fbits(lo), 0x07060302u);
}
// LDS byte address for logical (row, byte-col) in a [256][128B] tile (fallback).
__device__ __forceinline__ int swzb(int row, int bytecol) {
    return row * 128 + (bytecol ^ ((row & 7) << 4));
}

// global_load_lds, 16B per lane. LDS dst is wave-uniform; HW writes dst+lane*16.
__device__ __forceinline__ void gload_lds16(const void* g, void* s) {
    __builtin_amdgcn_global_load_lds(
        (const __attribute__((address_space(1))) void*)(uintptr_t)g,
        (__attribute__((address_space(3))) void*)(u32)(uintptr_t)s, 16, 0, 0);
}

#define WAIT_VM4()   do { asm volatile("s_waitcnt vmcnt(4)" ::: "memory");   \
                          __builtin_amdgcn_sched_barrier(0); } while (0)
#define WAIT_VM0()   do { asm volatile("s_waitcnt vmcnt(0)" ::: "memory");   \
                          __builtin_amdgcn_sched_barrier(0); } while (0)
#define BARRIER()    do { __builtin_amdgcn_s_barrier();                      \
                          __builtin_amdgcn_sched_barrier(0); } while (0)

// ---- pre-convert: W int32 -> bf16 (same layout) ----
__global__ __launch_bounds__(256)
void qlin_convert_w(const int* __restrict__ Wq, short* __restrict__ Wb)
{
    const size_t i = (size_t)blockIdx.x * 256 + threadIdx.x;   // 8 elts/thread
    i32x4 w0 = ((const i32x4*)Wq)[2 * i];
    i32x4 w1 = ((const i32x4*)Wq)[2 * i + 1];
    u32x4 q;
    q[0] = pack_bf16_trunc((float)w0[0], (float)w0[1]);
    q[1] = pack_bf16_trunc((float)w0[2], (float)w0[3]);
    q[2] = pack_bf16_trunc((float)w1[0], (float)w1[1]);
    q[3] = pack_bf16_trunc((float)w1[2], (float)w1[3]);
    ((u32x4*)Wb)[i] = q;
}

// ---- pre-convert: X f32 -> bf16 ----
__global__ __launch_bounds__(256)
void qlin_convert_x(const float* __restrict__ X, short* __restrict__ Xb)
{
    const size_t i = (size_t)blockIdx.x * 256 + threadIdx.x;   // 8 elts/thread
    f32x4 a = ((const f32x4*)X)[2 * i];
    f32x4 b = ((const f32x4*)X)[2 * i + 1];
    u32x4 q;
    q[0] = pack_bf16_trunc(a[0], a[1]);
    q[1] = pack_bf16_trunc(a[2], a[3]);
    q[2] = pack_bf16_trunc(b[0], b[1]);
    q[3] = pack_bf16_trunc(b[2], b[3]);
    ((u32x4*)Xb)[i] = q;
}

// ===================== main pipelined GEMM (bf16 inputs) =====================
// LDS per operand: [3 bufs][256 rows][64 B] = 16 KiB/buf; 96 KiB total.
// Storage swizzle (R7, measured-clean): 16B chunk H (0..3) of row R at byte
// R*64 + (H ^ ((R>>1)&3))*16. DMA writes linearly (lane i -> row seg*16+(i>>2),
// slot i&3), so the global source chunk is pre-swizzled: H = (i&3)^((i>>3)&3)
// (involution, rule 21). Reads use thread-constant slot offset.
__global__ __launch_bounds__(512, 2)
void qlin_gemm_p(const short* __restrict__ A, const short* __restrict__ B,
                 const float* __restrict__ scale_p, float* __restrict__ C)
{
    __shared__ __align__(16) char As[3][256 * 64];   // 48 KiB
    __shared__ __align__(16) char Bs[3][256 * 64];   // 48 KiB

    const int tid = threadIdx.x;
    // XCD swizzle: nwg = 512, divisible by 8 -> bijective
    const int nwg = (M_DIM / BM) * (N_DIM / BN);   // 512
    const int cpx = nwg / 8;
    const int bid = ((int)blockIdx.x % 8) * cpx + (int)blockIdx.x / 8;
    const int tileM = (bid / (N_DIM / BN)) * BM;
    const int tileN = (bid % (N_DIM / BN)) * BN;

    const int lane = tid & 63;
    const int wid  = tid >> 6;       // 0..7
    const int wr   = wid >> 2;       // 0..1  (wave covers 128 M-rows)
    const int wc   = wid & 3;        // 0..3  (wave covers 64 N-cols)
    const int lr   = lane & 15;
    const int lq   = lane >> 4;

    // staging: lane i covers row seg*16 + (i>>2), chunk H = (i&3)^((i>>3)&3)
    const int scol = (((lane & 3) ^ ((lane >> 3) & 3)) << 4);
    const char* Ag = (const char*)A;
    const char* Bg = (const char*)B;

    // stage one 16KB tile: 2 x global_load_lds per thread (8KB per wave-issue)
    auto stageA = [&](int buf, int kt) {
#pragma unroll
        for (int j = 0; j < 2; ++j) {
            const int seg = wid * 2 + j;           // 0..15 -> rows seg*16..+15
            const char* src = Ag + (size_t)(tileM + seg * 16 + (lane >> 2)) * (K_DIM * 2)
                                 + kt * (BKP * 2) + scol;
            gload_lds16(src, &As[buf][seg * 1024]);
        }
    };
    auto stageB = [&](int buf, int kt) {
#pragma unroll
        for (int j = 0; j < 2; ++j) {
            const int seg = wid * 2 + j;
            const char* src = Bg + (size_t)(tileN + seg * 16 + (lane >> 2)) * (K_DIM * 2)
                                 + kt * (BKP * 2) + scol;
            gload_lds16(src, &Bs[buf][seg * 1024]);
        }
    };

    // ---- fragments ----
    f32x4  acc[8][4] = {};
    bf16x8 afr[8], bn[4];

    // read slot offset: lq ^ ((row>>1)&3); row % 16 == lr for all frag rows,
    // so (row>>1)&3 == (lr>>1)&3 -> thread-constant byte offset in the row.
    const int roff = ((lq ^ ((lr >> 1) & 3)) << 4);

    auto ldA1 = [&](int buf, int m) {
        const int row = wr * 128 + m * 16 + lr;
        afr[m] = *(const bf16x8*)&As[buf][row * 64 + roff];
    };
    auto ldB4 = [&](int buf) {
#pragma unroll
        for (int nb = 0; nb < 4; ++nb) {
            const int row = wc * 64 + nb * 16 + lr;
            bn[nb] = *(const bf16x8*)&Bs[buf][row * 64 + roff];
        }
    };
    // 16 MFMA: (mlo..mlo+3) x all 4 n-blocks, K=32 in one shot
    auto cluster = [&](int mlo) {
        __builtin_amdgcn_s_setprio(1);
#pragma unroll
        for (int m = 0; m < 4; ++m)
#pragma unroll
            for (int n = 0; n < 4; ++n)
                acc[mlo + m][n] = __builtin_amdgcn_mfma_f32_16x16x32_bf16(
                    afr[mlo + m], bn[n], acc[mlo + m][n], 0, 0, 0);
        __builtin_amdgcn_s_setprio(0);
    };

    // ---- prologue: tile0 -> buf0, tile1 -> buf1 ----
    stageA(0, 0); stageB(0, 0);      // 4 issues
    stageA(1, 1); stageB(1, 1);      // 4 issues
    WAIT_VM4();        // tile0 landed; tile1's 4 loads in flight
    BARRIER();

    // ---- main loop: ONE barrier + one counted vmcnt per K-tile ----
    // Entry invariant tile t: A(t),B(t) resident in buf t%3 (guaranteed by the
    // vmcnt at end of t-1, which drains everything except t+1's 4 loads);
    // t+1's loads in flight toward buf (t+1)%3.
    // Body: stage t+2 into buf (t+2)%3 -- NO reader of that buf this tile
    // (its last readers were tile t-1, behind the end-of-t-1 barrier), so no
    // mid-tile sync is needed. End: vmcnt(4) leaves t+2's loads (issued this
    // tile) in flight and drains t+1's (issued a full tile ago -> no stall).
    int cur = 0, pre = 2;            // cur = kt%3, pre = (kt+2)%3
#pragma unroll 1
    for (int kt = 0; kt < NTP; ++kt) {
        const bool more = (kt + 2) < NTP;

        if (more) stageA(pre, kt + 2);           // 2 VMEM issues
        ldB4(cur);                               // 4 ds_reads
        ldA1(cur, 0); ldA1(cur, 1); ldA1(cur, 2); ldA1(cur, 3);
        ldA1(cur, 4); ldA1(cur, 5); ldA1(cur, 6); ldA1(cur, 7);
        if (more) stageB(pre, kt + 2);           // 2 VMEM issues

        cluster(0);                              // 16 MFMA
        cluster(4);                              // 16 MFMA

        if (more) { WAIT_VM4(); } else { WAIT_VM0(); }
        BARRIER();                               // single tile-boundary sync

        cur = (cur == 2) ? 0 : cur + 1;
        pre = (pre == 2) ? 0 : pre + 1;
    }

    // ---- epilogue: C/D layout col=lane&15, row=(lane>>4)*4+reg ----
    const float scl = scale_p[0];
#pragma unroll
    for (int m = 0; m < 8; ++m) {
        const int gm0 = tileM + wr * 128 + m * 16 + lq * 4;
#pragma unroll
        for (int n = 0; n < 4; ++n) {
            const int gn = tileN + wc * 64 + n * 16 + lr;
            float* cp = C + (size_t)gm0 * N_DIM + gn;
#pragma unroll
            for (int r = 0; r < 4; ++r)
                cp[(size_t)r * N_DIM] = acc[m][n][r] * scl;
        }
    }
}

// ===================== fallback (no workspace): reg-staged kernel ============
#define TILE_BYTES (BM * BK * 2)
__global__ __launch_bounds__(512, 2)
void qlin_gemm8(const void* __restrict__ Asrc, const void* __restrict__ Bsrc,
                const float* __restrict__ scale_p, float* __restrict__ C)
{
    __shared__ char As[2 * TILE_BYTES];
    __shared__ char Bs[2 * TILE_BYTES];

    const int tid = threadIdx.x;
    const int nwg = (M_DIM / BM) * (N_DIM / BN);
    const int cpx = nwg / 8;
    const int bid = ((int)blockIdx.x % 8) * cpx + (int)blockIdx.x / 8;
    const int tileM = (bid / (N_DIM / BN)) * BM;
    const int tileN = (bid % (N_DIM / BN)) * BN;

    const int lane = tid & 63;
    const int wid  = tid >> 6;
    const int wr   = wid >> 2;
    const int wc   = wid & 3;
    const int lr   = lane & 15;
    const int lq   = lane >> 4;

    f32x4  aF[8]; i32x4 wF[8];

    const float* ag0 = (const float*)Asrc + (size_t)(tileM + (tid >> 4)) * K_DIM + (tid & 15) * 4;
    const int*   bg0 = (const int*)Bsrc  + (size_t)(tileN + (tid >> 4)) * K_DIM + (tid & 15) * 4;

    auto stage_load = [&](int kt) {
#pragma unroll
        for (int i = 0; i < 8; ++i)
            aF[i] = *(const f32x4*)(ag0 + (size_t)(32 * i) * K_DIM + kt * BK);
#pragma unroll
        for (int i = 0; i < 8; ++i)
            wF[i] = *(const i32x4*)(bg0 + (size_t)(32 * i) * K_DIM + kt * BK);
    };
    auto stage_writeA = [&](int nxt) {
        char* dst = As + nxt * TILE_BYTES;
#pragma unroll
        for (int i = 0; i < 8; ++i) {
            u32x2 p;
            p[0] = pack_bf16_trunc(aF[i][0], aF[i][1]);
            p[1] = pack_bf16_trunc(aF[i][2], aF[i][3]);
            *(u32x2*)(dst + swzb((tid >> 4) + 32 * i, (tid & 15) * 8)) = p;
        }
    };
    auto stage_writeB = [&](int nxt) {
        char* dst = Bs + nxt * TILE_BYTES;
#pragma unroll
        for (int i = 0; i < 8; ++i) {
            u32x2 p;
            p[0] = pack_bf16_trunc((float)wF[i][0], (float)wF[i][1]);
            p[1] = pack_bf16_trunc((float)wF[i][2], (float)wF[i][3]);
            *(u32x2*)(dst + swzb((tid >> 4) + 32 * i, (tid & 15) * 8)) = p;
        }
    };

    f32x4  acc[8][4] = {};
    bf16x8 afr[4][2], bfr[2][2];

    auto ldA = [&](const char* buf, int mb) {
#pragma unroll
        for (int m = 0; m < 4; ++m) {
            const int row = wr * 128 + (mb + m) * 16 + lr;
#pragma unroll
            for (int ks = 0; ks < 2; ++ks)
                afr[m][ks] = *(const bf16x8*)(buf + swzb(row, ks * 64 + lq * 16));
        }
    };
    auto ldB = [&](const char* buf, int nb) {
#pragma unroll
        for (int n = 0; n < 2; ++n) {
            const int row = wc * 64 + (nb + n) * 16 + lr;
#pragma unroll
            for (int ks = 0; ks < 2; ++ks)
                bfr[n][ks] = *(const bf16x8*)(buf + swzb(row, ks * 64 + lq * 16));
        }
    };
    auto quad = [&](int mb, int nb) {
        __builtin_amdgcn_s_setprio(1);
#pragma unroll
        for (int m = 0; m < 4; ++m)
#pragma unroll
            for (int n = 0; n < 2; ++n)
#pragma unroll
                for (int ks = 0; ks < 2; ++ks)
                    acc[mb + m][nb + n] = __builtin_amdgcn_mfma_f32_16x16x32_bf16(
                        afr[m][ks], bfr[n][ks], acc[mb + m][nb + n], 0, 0, 0);
        __builtin_amdgcn_s_setprio(0);
    };

    stage_load(0);
    stage_writeA(0);
    stage_writeB(0);
    __syncthreads();

#pragma unroll 1
    for (int kt = 0; kt < NT; ++kt) {
        const int cur = kt & 1, nxt = cur ^ 1;
        const bool more = (kt + 1) < NT;
        const char* Ab = As + cur * TILE_BYTES;
        const char* Bb = Bs + cur * TILE_BYTES;

        if (more) stage_load(kt + 1);

        ldA(Ab, 0); ldB(Bb, 0); quad(0, 0);
        ldB(Bb, 2);             quad(0, 2);
        ldA(Ab, 4);
        if (more) stage_writeA(nxt);
        quad(4, 2);
        ldB(Bb, 0);
        if (more) stage_writeB(nxt);
        quad(4, 0);

        __syncthreads();
    }

    const float scl = scale_p[0];
#pragma unroll
    for (int m = 0; m < 8; ++m) {
        const int gm0 = tileM + wr * 128 + m * 16 + lq * 4;
#pragma unroll
        for (int n = 0; n < 4; ++n) {
            const int gn = tileN + wc * 64 + n * 16 + lr;
            float* cp = C + (size_t)gm0 * N_DIM + gn;
#pragma unroll
            for (int r = 0; r < 4; ++r)
                cp[(size_t)r * N_DIM] = acc[m][n][r] * scl;
        }
    }
}

extern "C" void kernel_launch(void* const* d_in, const int* in_sizes, int n_in,
                              void* d_out, int out_size, void* d_ws, size_t ws_size,
                              hipStream_t stream)
{
    (void)in_sizes; (void)n_in; (void)out_size;
    const float* X     = (const float*)d_in[0];
    const int*   Wq    = (const int*)d_in[1];      // int8-valued, delivered as int32
    const float* scale = (const float*)d_in[2];
    float* C = (float*)d_out;

    const dim3 gblock(256);
    const dim3 ggrid((M_DIM / BM) * (N_DIM / BN));  // 512
    const size_t xbytes = (size_t)M_DIM * K_DIM * sizeof(short);   // 64 MiB
    const size_t wbytes = (size_t)N_DIM * K_DIM * sizeof(short);   // 32 MiB

    if (ws_size >= xbytes + wbytes) {
        short* Xb = (short*)d_ws;
        short* Wb = (short*)((char*)d_ws + xbytes);
        qlin_convert_x<<<dim3((size_t)M_DIM * K_DIM / (8 * 256)), gblock, 0, stream>>>(X, Xb);
        qlin_convert_w<<<dim3((size_t)N_DIM * K_DIM / (8 * 256)), gblock, 0, stream>>>(Wq, Wb);
        qlin_gemm_p<<<ggrid, dim3(512), 0, stream>>>(Xb, Wb, scale, C);
    } else {
        qlin_gemm8<<<ggrid, dim3(512), 0, stream>>>(X, Wq, scale, C);
    }
}